// Round 4
// baseline (609.157 us; speedup 1.0000x reference)
//
#include <hip/hip_runtime.h>
#include <hip/hip_bf16.h>

#define S_LEN 2048
#define HID   4096
#define NH    32
#define NKV   8
#define HD    128
#define QKV_N 6144
#define KDIM  4096

typedef __attribute__((ext_vector_type(8))) short short8;
typedef __attribute__((ext_vector_type(4))) float floatx4;
typedef unsigned short ushort;

__device__ __forceinline__ unsigned short f2bu(float f) {
  __hip_bfloat16 b = __float2bfloat16(f);
  return *reinterpret_cast<unsigned short*>(&b);
}
__device__ __forceinline__ void store_c(float* p, float v) { *p = v; }
__device__ __forceinline__ void store_c(__hip_bfloat16* p, float v) { *p = __float2bfloat16(v); }

__device__ __forceinline__ void async_copy16(const void* g, void* l) {
  __builtin_amdgcn_global_load_lds((const __attribute__((address_space(1))) void*)g,
                                   (__attribute__((address_space(3))) void*)l, 16, 0, 0);
}

// ---------------- fp32 -> bf16 convert ----------------
struct bf16x4 { __hip_bfloat16 a, b, c, d; };
__global__ void cvt_f32_bf16(const float* __restrict__ src, __hip_bfloat16* __restrict__ dst, int n4) {
  int i = blockIdx.x * blockDim.x + threadIdx.x;
  if (i < n4) {
    float4 v = ((const float4*)src)[i];
    bf16x4 o = { __float2bfloat16(v.x), __float2bfloat16(v.y),
                 __float2bfloat16(v.z), __float2bfloat16(v.w) };
    ((bf16x4*)dst)[i] = o;
  }
}

// ---------------- NT bf16 GEMM, BK=64, swizzled LDS, global_load_lds staging ----------------
template <typename CT>
__global__ __launch_bounds__(256, 2) void gemm_nt(const __hip_bfloat16* __restrict__ A,
                                                  const __hip_bfloat16* __restrict__ B,
                                                  CT* __restrict__ C, int M, int N, int K) {
  __shared__ __align__(16) ushort As[128 * 64];
  __shared__ __align__(16) ushort Bs[128 * 64];
  const int tid  = threadIdx.x;
  const int bm   = blockIdx.y * 128;
  const int bn   = blockIdx.x * 128;
  const int wave = tid >> 6;
  const int lane = tid & 63;
  const int ww   = (wave >> 1) * 64;
  const int wc   = (wave & 1) * 64;
  const int l15  = lane & 15;
  const int quad = lane >> 4;

  const ushort* Au = (const ushort*)A;
  const ushort* Bu = (const ushort*)B;

  const int rr  = lane >> 3;
  const int cc  = lane & 7;
  const int gch = cc ^ rr;
  const ushort* Ag = Au + (size_t)(bm + wave * 32 + rr) * K + gch * 8;
  const ushort* Bg = Bu + (size_t)(bn + wave * 32 + rr) * K + gch * 8;

  floatx4 acc[4][4] = {};

  for (int k0 = 0; k0 < K; k0 += 64) {
    __syncthreads();
#pragma unroll
    for (int e = 0; e < 4; ++e) {
      async_copy16(Ag + (size_t)(e * 8) * K + k0, &As[(wave * 32 + e * 8) * 64]);
      async_copy16(Bg + (size_t)(e * 8) * K + k0, &Bs[(wave * 32 + e * 8) * 64]);
    }
    __syncthreads();
#pragma unroll
    for (int kd = 0; kd < 2; ++kd) {
      short8 af[4], bf[4];
#pragma unroll
      for (int i = 0; i < 4; ++i) {
        af[i] = *(const short8*)&As[(ww + i * 16 + l15) * 64 + ((kd * 4 + quad) ^ (l15 & 7)) * 8];
        bf[i] = *(const short8*)&Bs[(wc + i * 16 + l15) * 64 + ((kd * 4 + quad) ^ (l15 & 7)) * 8];
      }
#pragma unroll
      for (int mi = 0; mi < 4; ++mi)
#pragma unroll
        for (int ni = 0; ni < 4; ++ni)
          acc[mi][ni] = __builtin_amdgcn_mfma_f32_16x16x32_bf16(af[mi], bf[ni], acc[mi][ni], 0, 0, 0);
    }
  }
#pragma unroll
  for (int mi = 0; mi < 4; ++mi)
#pragma unroll
    for (int ni = 0; ni < 4; ++ni)
#pragma unroll
      for (int r = 0; r < 4; ++r) {
        int row = bm + ww + mi * 16 + quad * 4 + r;
        int col = bn + wc + ni * 16 + l15;
        store_c(&C[(size_t)row * N + col], acc[mi][ni][r]);
      }
}

// ---------------- RoPE for q,k -> head-major layouts ----------------
__global__ void rope_qk(const __hip_bfloat16* __restrict__ QKV,
                        const float* __restrict__ cosp, const float* __restrict__ sinp,
                        __hip_bfloat16* __restrict__ Qh, __hip_bfloat16* __restrict__ Kh) {
  int s = blockIdx.y;
  int col = blockIdx.x * 256 + threadIdx.x;
  if (col >= 5120) return;
  const size_t base = (size_t)s * QKV_N;
  float x = __bfloat162float(QKV[base + col]);
  int dd = col & 127;
  float val;
  if (dd < 64) {
    float xp = __bfloat162float(QKV[base + col + 64]);
    val = x * cosp[s * 64 + dd] - xp * sinp[s * 64 + dd];
  } else {
    int f = dd - 64;
    float xp = __bfloat162float(QKV[base + col - 64]);
    val = x * cosp[s * 64 + f] + xp * sinp[s * 64 + f];
  }
  if (col < HID) {
    int h = col >> 7;
    Qh[((size_t)h * S_LEN + s) * HD + dd] = __float2bfloat16(val);
  } else {
    int h = (col - HID) >> 7;
    Kh[((size_t)h * S_LEN + s) * HD + dd] = __float2bfloat16(val);
  }
}

// ---------------- V transpose: QKV[s][5120+h*128+d] -> Vt[h][d][s] ----------------
__global__ void v_transpose(const __hip_bfloat16* __restrict__ QKV, __hip_bfloat16* __restrict__ Vt) {
  __shared__ ushort tile[64][130];
  int h = blockIdx.y;
  int s0 = blockIdx.x * 64;
  int t = threadIdx.x;
  const ushort* src = (const ushort*)QKV;
#pragma unroll
  for (int i = 0; i < 32; ++i) {
    int flat = i * 256 + t;
    int r = flat >> 7, c = flat & 127;
    tile[r][c] = src[(size_t)(s0 + r) * QKV_N + 5120 + h * 128 + c];
  }
  __syncthreads();
  ushort* dst = (ushort*)Vt;
#pragma unroll
  for (int i = 0; i < 8; ++i) {
    int g = i * 256 + t;
    int d = g >> 4, j4 = (g & 15) * 4;
    ushort4 o;
    o.x = tile[j4][d]; o.y = tile[j4 + 1][d]; o.z = tile[j4 + 2][d]; o.w = tile[j4 + 3][d];
    *(ushort4*)&dst[((size_t)h * HD + d) * S_LEN + s0 + j4] = o;
  }
}

// ---------------- flash attention v4 ----------------
// 1024 blocks: 64-row q-tiles, 4 waves x 16 rows, K-step 32, K in dbuf LDS,
// log2-domain softmax, lazy l-reduction, ballot-gated rescale.
__global__ __launch_bounds__(256, 4) void attn(const __hip_bfloat16* __restrict__ Qh,
                                               const __hip_bfloat16* __restrict__ Kh,
                                               const __hip_bfloat16* __restrict__ Vt,
                                               __hip_bfloat16* __restrict__ AO) {
  __shared__ __align__(16) ushort Ks[2][32][128];  // [row][chunk c] = global chunk c^(row&15)
  __shared__ __align__(16) ushort P[4][16][40];    // stride 40 shorts = 80B, 16B-aligned
  const int bi   = blockIdx.x;                     // 0..1023
  const int head = bi & 31;
  const int tile = 31 - ((bi >> 5) & 31);          // heavy tiles first
  const int wave = threadIdx.x >> 6;
  const int lane = threadIdx.x & 63;
  const int l15 = lane & 15, quad = lane >> 4;
  const int q0 = tile * 64 + wave * 16;            // wave's 16 q rows
  const int hk = head & 7;
  const ushort* Qu = (const ushort*)Qh + (size_t)head * S_LEN * HD;
  const ushort* Ku = (const ushort*)Kh + (size_t)hk * S_LEN * HD;
  const ushort* Vu = (const ushort*)Vt + (size_t)hk * HD * S_LEN;

  const int rr4  = lane >> 4;
  const int cc16 = lane & 15;

  short8 qf[4];
#pragma unroll
  for (int kd = 0; kd < 4; ++kd)
    qf[kd] = *(const short8*)(Qu + (size_t)(q0 + l15) * HD + kd * 32 + quad * 8);

  floatx4 o[8] = {};
  float mst[4], lsum[4];
#pragma unroll
  for (int r = 0; r < 4; ++r) { mst[r] = -1e30f; lsum[r] = 0.f; }

  const float c2 = 0.08838834764831845f * 1.4426950408889634f;  // scale*log2(e)
  const int nsteps = 2 * tile + 2;
  const int jendw = q0 + 16;

  auto stage = [&](int b, int j0) {
#pragma unroll
    for (int e = 0; e < 2; ++e) {
      int rt = e * 4 + rr4;                        // 0..7 within wave's 8 rows
      int row = wave * 8 + rt;
      int gc = cc16 ^ (row & 15);
      async_copy16(Ku + (size_t)(j0 + row) * HD + gc * 8, &Ks[b][wave * 8 + e * 4][0]);
    }
  };
  stage(0, 0);

  for (int s = 0; s < nsteps; ++s) {
    const int j0 = s * 32;
    __syncthreads();
    if (s + 1 < nsteps) stage((s + 1) & 1, j0 + 32);
    if (j0 >= jendw) continue;                     // wave-uniform
    const int b = s & 1;

    // first-half V loads early (L2 latency hides under QK+softmax)
    short8 vfa[4];
#pragma unroll
    for (int t = 0; t < 4; ++t)
      vfa[t] = *(const short8*)(Vu + (size_t)(t * 16 + l15) * S_LEN + j0 + quad * 8);

    floatx4 sc[2];
#pragma unroll
    for (int nt = 0; nt < 2; ++nt) {
      sc[nt] = floatx4{0.f, 0.f, 0.f, 0.f};
      short8 kf[4];
#pragma unroll
      for (int kd = 0; kd < 4; ++kd)
        kf[kd] = *(const short8*)&Ks[b][nt * 16 + l15][((kd * 4 + quad) ^ l15) * 8];
#pragma unroll
      for (int kd = 0; kd < 4; ++kd)
        sc[nt] = __builtin_amdgcn_mfma_f32_16x16x32_bf16(qf[kd], kf[kd], sc[nt], 0, 0, 0);
    }

    const bool domask = (j0 + 32 > q0);
    float v0[4], v1[4], mnew[4];
    bool ch = false;
#pragma unroll
    for (int r = 0; r < 4; ++r) {
      const int row = q0 + quad * 4 + r;
      float a = sc[0][r] * c2;
      float bb = sc[1][r] * c2;
      if (domask) {
        if (j0 + l15 > row) a = -1e30f;
        if (j0 + 16 + l15 > row) bb = -1e30f;
      }
      v0[r] = a; v1[r] = bb;
      float vm = fmaxf(a, bb);
      vm = fmaxf(vm, __shfl_xor(vm, 1));
      vm = fmaxf(vm, __shfl_xor(vm, 2));
      vm = fmaxf(vm, __shfl_xor(vm, 4));
      vm = fmaxf(vm, __shfl_xor(vm, 8));
      mnew[r] = fmaxf(mst[r], vm);
      ch |= (mnew[r] > mst[r]);
    }
    float psr[4];
#pragma unroll
    for (int r = 0; r < 4; ++r) {
      float p0 = exp2f(v0[r] - mnew[r]);
      float p1 = exp2f(v1[r] - mnew[r]);
      P[wave][quad * 4 + r][l15] = f2bu(p0);
      P[wave][quad * 4 + r][16 + l15] = f2bu(p1);
      psr[r] = p0 + p1;                            // per-lane partial row-sum
    }
    if (__ballot(ch)) {
#pragma unroll
      for (int r = 0; r < 4; ++r) {
        float alpha = exp2f(mst[r] - mnew[r]);
        lsum[r] = lsum[r] * alpha + psr[r];
        mst[r] = mnew[r];
#pragma unroll
        for (int t = 0; t < 8; ++t) o[t][r] *= alpha;
      }
    } else {
#pragma unroll
      for (int r = 0; r < 4; ++r) lsum[r] += psr[r];
    }

    // second-half V loads
    short8 vfb[4];
#pragma unroll
    for (int t = 0; t < 4; ++t)
      vfb[t] = *(const short8*)(Vu + (size_t)((t + 4) * 16 + l15) * S_LEN + j0 + quad * 8);

    asm volatile("s_waitcnt lgkmcnt(0)" ::: "memory");
    short8 pf = *(const short8*)&P[wave][l15][quad * 8];
#pragma unroll
    for (int t = 0; t < 4; ++t)
      o[t] = __builtin_amdgcn_mfma_f32_16x16x32_bf16(pf, vfa[t], o[t], 0, 0, 0);
#pragma unroll
    for (int t = 0; t < 4; ++t)
      o[t + 4] = __builtin_amdgcn_mfma_f32_16x16x32_bf16(pf, vfb[t], o[t + 4], 0, 0, 0);
  }

#pragma unroll
  for (int r = 0; r < 4; ++r) {
    float ls = lsum[r];
    ls += __shfl_xor(ls, 1);
    ls += __shfl_xor(ls, 2);
    ls += __shfl_xor(ls, 4);
    ls += __shfl_xor(ls, 8);
    const float inv = 1.0f / ls;
    const int row = q0 + quad * 4 + r;
#pragma unroll
    for (int t = 0; t < 8; ++t)
      AO[(size_t)row * HID + head * HD + t * 16 + l15] = __float2bfloat16(o[t][r] * inv);
  }
}

extern "C" void kernel_launch(void* const* d_in, const int* in_sizes, int n_in,
                              void* d_out, int out_size, void* d_ws, size_t ws_size,
                              hipStream_t stream) {
  const float* x    = (const float*)d_in[0];
  const float* wq   = (const float*)d_in[1];
  const float* wk   = (const float*)d_in[2];
  const float* wv   = (const float*)d_in[3];
  const float* wo   = (const float*)d_in[4];
  const float* cosp = (const float*)d_in[5];
  const float* sinp = (const float*)d_in[6];
  float* out = (float*)d_out;

  char* ws = (char*)d_ws;
  size_t off = 0;
  auto alloc = [&](size_t bytes) { char* p = ws + off; off += (bytes + 255) & ~255ull; return p; };
  __hip_bfloat16* Xb   = (__hip_bfloat16*)alloc((size_t)S_LEN * KDIM * 2);
  __hip_bfloat16* Wqkv = (__hip_bfloat16*)alloc((size_t)QKV_N * KDIM * 2);
  __hip_bfloat16* Wob  = (__hip_bfloat16*)alloc((size_t)HID * HID * 2);
  __hip_bfloat16* QKVb = (__hip_bfloat16*)alloc((size_t)S_LEN * QKV_N * 2);
  __hip_bfloat16* Qh   = (__hip_bfloat16*)alloc((size_t)NH * S_LEN * HD * 2);
  __hip_bfloat16* Kh   = (__hip_bfloat16*)alloc((size_t)NKV * S_LEN * HD * 2);
  __hip_bfloat16* Vt   = (__hip_bfloat16*)alloc((size_t)NKV * HD * S_LEN * 2);
  __hip_bfloat16* AO   = (__hip_bfloat16*)alloc((size_t)S_LEN * HID * 2);

  auto cvt = [&](const float* s, __hip_bfloat16* dpt, size_t n) {
    int n4 = (int)(n / 4);
    cvt_f32_bf16<<<dim3((n4 + 255) / 256), dim3(256), 0, stream>>>(s, dpt, n4);
  };
  cvt(x, Xb, (size_t)S_LEN * KDIM);
  cvt(wq, Wqkv, (size_t)HID * KDIM);
  cvt(wk, Wqkv + (size_t)HID * KDIM, (size_t)NKV * HD * KDIM);
  cvt(wv, Wqkv + (size_t)(HID + NKV * HD) * KDIM, (size_t)NKV * HD * KDIM);
  cvt(wo, Wob, (size_t)HID * HID);

  gemm_nt<__hip_bfloat16><<<dim3(QKV_N / 128, S_LEN / 128), dim3(256), 0, stream>>>(
      Xb, Wqkv, QKVb, S_LEN, QKV_N, KDIM);
  rope_qk<<<dim3(20, S_LEN), dim3(256), 0, stream>>>(QKVb, cosp, sinp, Qh, Kh);
  v_transpose<<<dim3(S_LEN / 64, NKV), dim3(256), 0, stream>>>(QKVb, Vt);
  attn<<<dim3(1024), dim3(256), 0, stream>>>(Qh, Kh, Vt, AO);
  gemm_nt<float><<<dim3(HID / 128, S_LEN / 128), dim3(256), 0, stream>>>(
      AO, Wob, out, S_LEN, HID, KDIM);
}